// Round 13
// baseline (513.704 us; speedup 1.0000x reference)
//
#include <hip/hip_runtime.h>
#include <hip/hip_bf16.h>

#define S_LEN 4096
#define DM    512
#define NH    8
#define DK    64

typedef __attribute__((ext_vector_type(8))) __bf16 bf16x8;
typedef __attribute__((ext_vector_type(4))) float  f32x4;
typedef unsigned short u16;
typedef unsigned int   u32;
typedef unsigned long long u64;

// Q-GEMM epilogue scale: 1/sqrt(64) * log2(e)  (softmax in log2 domain)
#define SQ_SCALE (0.125f * 1.44269504f)
// Fixed softmax shift (log2-domain). Shift-invariant; l-division restores scale.
#define FMAX 12.0f

__device__ __forceinline__ u16 f2bf(float f) {
  union { float f; u32 i; } v; v.f = f;
  u32 r = v.i + 0x7fff + ((v.i >> 16) & 1);   // RNE
  return (u16)(r >> 16);
}
__device__ __forceinline__ float bf2f(u16 u) {
  union { u32 i; float f; } v; v.i = ((u32)u) << 16; return v.f;
}

// ---------------------------------------------------------------------------
// Fused prep: blocks [0,65536) pack mask int32 -> u64 bitmask;
// blocks [65536,68608) convert fp32 -> bf16 (x | wq|wk|wv -> wcat | dw).
__global__ __launch_bounds__(256) void prep(
    const int* __restrict__ mask, u64* __restrict__ mb,
    const float* __restrict__ x, const float* __restrict__ wq,
    const float* __restrict__ wk, const float* __restrict__ wv,
    const float* __restrict__ dw,
    u16* __restrict__ xb, u16* __restrict__ wcat, u16* __restrict__ dwb) {
  int b = blockIdx.x;
  if (b < 65536) {
    int gid = b * 256 + threadIdx.x;
    u64 bb = __ballot(mask[gid] != 0);
    if ((threadIdx.x & 63) == 0) mb[gid >> 6] = bb;
  } else {
    b -= 65536;
    const float* src; u16* dst; size_t off;
    if      (b < 2048) { src = x;  dst = xb;   off = (size_t)b * 1024; }
    else if (b < 2304) { src = wq; dst = wcat; off = (size_t)(b - 2048) * 1024; }
    else if (b < 2560) { src = wk; dst = wcat + 262144; off = (size_t)(b - 2304) * 1024; }
    else if (b < 2816) { src = wv; dst = wcat + 524288; off = (size_t)(b - 2560) * 1024; }
    else               { src = dw; dst = dwb;  off = (size_t)(b - 2816) * 1024; }
    size_t i = off + (size_t)threadIdx.x * 4;
    float4 v = *reinterpret_cast<const float4*>(src + i);
    ushort4 o = make_ushort4(f2bf(v.x), f2bf(v.y), f2bf(v.z), f2bf(v.w));
    *reinterpret_cast<ushort4*>(dst + i) = o;
  }
}

// ---------------------------------------------------------------------------
// Fused QKV projection, 64(m) x 128(n) tiles: C[4096,1536] = x @ Wcat^T + bias.
// grid (12, 64). seg 0=Q (scaled), 1=K, 2=V.
// V output layout V4[(h*64+d)][tile*64 + slot] where for true key kappa =
// m'*8+c (from _split_heads: h=m>>9, d=n&63, key=(m&511)*8+(n>>6)):
// tile = m'>>3, slot = (c&1)*32 + (c>>1)*8 + (m'&7).  This slot order makes
// attn's P C-layout directly usable as the PV A-fragment (see attn_mfma).
__global__ __launch_bounds__(256) void qkv_gemm(
    const u16* __restrict__ A, const u16* __restrict__ Wcat,
    const float* __restrict__ bq, const float* __restrict__ bk,
    const float* __restrict__ bv,
    u16* __restrict__ Qb, u16* __restrict__ Kb, u16* __restrict__ V4) {
  __shared__ u16 As[64 * 72];    // 9.2 KB
  __shared__ u16 Ws[128 * 72];   // 18.4 KB (reused as T in V epilogue)
  const int t = threadIdx.x;
  const int lane = t & 63, wv = t >> 6;
  const int m16 = lane & 15, quad = lane >> 4;
  const int n0g = blockIdx.x * 128, m0 = blockIdx.y * 64;
  const int seg = n0g >> 9;
  const int n0 = n0g & 511;
  const int mq = wv >> 1, nq = wv & 1;   // wave quadrant

  f32x4 acc[2][4];
#pragma unroll
  for (int i = 0; i < 2; i++)
#pragma unroll
    for (int j = 0; j < 4; j++) acc[i][j] = (f32x4)0.f;

  for (int k0 = 0; k0 < DM; k0 += 64) {
    __syncthreads();
#pragma unroll
    for (int c0 = 0; c0 < 2; c0++) {       // A: 64x64 = 512 uint4
      int c = t + c0 * 256;
      int row = c >> 3, col = (c & 7) * 8;
      *reinterpret_cast<uint4*>(&As[row * 72 + col]) =
          *reinterpret_cast<const uint4*>(&A[(size_t)(m0 + row) * DM + k0 + col]);
    }
#pragma unroll
    for (int c0 = 0; c0 < 4; c0++) {       // W: 128x64 = 1024 uint4
      int c = t + c0 * 256;
      int row = c >> 3, col = (c & 7) * 8;
      *reinterpret_cast<uint4*>(&Ws[row * 72 + col]) =
          *reinterpret_cast<const uint4*>(&Wcat[(size_t)(n0g + row) * DM + k0 + col]);
    }
    __syncthreads();
#pragma unroll
    for (int kk = 0; kk < 64; kk += 32) {
      bf16x8 a0 = *reinterpret_cast<const bf16x8*>(&As[(mq * 32 + m16) * 72 + quad * 8 + kk]);
      bf16x8 a1 = *reinterpret_cast<const bf16x8*>(&As[(mq * 32 + 16 + m16) * 72 + quad * 8 + kk]);
#pragma unroll
      for (int ct = 0; ct < 4; ct++) {
        bf16x8 b = *reinterpret_cast<const bf16x8*>(&Ws[(nq * 64 + ct * 16 + m16) * 72 + quad * 8 + kk]);
        acc[0][ct] = __builtin_amdgcn_mfma_f32_16x16x32_bf16(a0, b, acc[0][ct], 0, 0, 0);
        acc[1][ct] = __builtin_amdgcn_mfma_f32_16x16x32_bf16(a1, b, acc[1][ct], 0, 0, 0);
      }
    }
  }

  const float* bias = (seg == 0) ? bq : (seg == 1) ? bk : bv;
  const float scale = (seg == 0) ? SQ_SCALE : 1.f;
  float bn[4];
#pragma unroll
  for (int ct = 0; ct < 4; ct++) bn[ct] = bias[n0 + nq * 64 + ct * 16 + m16];

  if (seg == 2) {
    // transpose through LDS (reuse Ws as T[128 nl][64 ml], stride 72)
    __syncthreads();   // all fragment reads of Ws done
    u16* T = Ws;
#pragma unroll
    for (int rt = 0; rt < 2; rt++)
#pragma unroll
      for (int ct = 0; ct < 4; ct++)
#pragma unroll
        for (int r = 0; r < 4; r++)
          T[(nq * 64 + ct * 16 + m16) * 72 + mq * 32 + rt * 16 + quad * 4 + r] =
              f2bf(acc[rt][ct][r] + bn[ct]);
    __syncthreads();
    const int h    = m0 >> 9;
    const int mp   = m0 & 511;   // multiple of 64
    const int cseg = n0 >> 7;    // 0..3
#pragma unroll
    for (int c0 = 0; c0 < 4; c0++) {       // 1024 uint4 copies
      int c = t + c0 * 256;
      int d  = c >> 4;          // 0..63
      int tl = (c >> 1) & 7;    // 0..7
      int cl = c & 1;           // 0..1
      uint4 v = *reinterpret_cast<const uint4*>(&T[(cl * 64 + d) * 72 + tl * 8]);
      *reinterpret_cast<uint4*>(
          &V4[(size_t)(h * 64 + d) * 4096 + ((mp >> 3) + tl) * 64 + cl * 32 + cseg * 8]) = v;
    }
  } else {
    u16* dst = (seg == 0) ? Qb : Kb;
#pragma unroll
    for (int rt = 0; rt < 2; rt++)
#pragma unroll
      for (int ct = 0; ct < 4; ct++) {
        int n = n0 + nq * 64 + ct * 16 + m16;
#pragma unroll
        for (int r = 0; r < 4; r++) {
          int m = m0 + mq * 32 + rt * 16 + quad * 4 + r;
          dst[(size_t)m * DM + n] = f2bf((acc[rt][ct][r] + bn[ct]) * scale);
        }
      }
  }
}

// ---------------------------------------------------------------------------
// Dense out-proj, 64x64 tiles: C[4096,512](f32) = A @ dw^T + db. grid (8,64).
__global__ __launch_bounds__(256) void dense_gemm(
    const u16* __restrict__ A, const u16* __restrict__ W,
    const float* __restrict__ bias, float* __restrict__ Cout) {
  __shared__ u16 As[64 * 72];
  __shared__ u16 Ws[64 * 72];
  const int t = threadIdx.x;
  const int lane = t & 63, wv = t >> 6;
  const int m16 = lane & 15, quad = lane >> 4;
  const int n0 = blockIdx.x * 64, m0 = blockIdx.y * 64;

  f32x4 acc[4];
#pragma unroll
  for (int j = 0; j < 4; j++) acc[j] = (f32x4)0.f;

  for (int k0 = 0; k0 < DM; k0 += 64) {
    __syncthreads();
#pragma unroll
    for (int c0 = 0; c0 < 2; c0++) {
      int c = t + c0 * 256;
      int row = c >> 3, col = (c & 7) * 8;
      *reinterpret_cast<uint4*>(&As[row * 72 + col]) =
          *reinterpret_cast<const uint4*>(&A[(size_t)(m0 + row) * DM + k0 + col]);
      *reinterpret_cast<uint4*>(&Ws[row * 72 + col]) =
          *reinterpret_cast<const uint4*>(&W[(size_t)(n0 + row) * DM + k0 + col]);
    }
    __syncthreads();
#pragma unroll
    for (int kk = 0; kk < 64; kk += 32) {
      bf16x8 a = *reinterpret_cast<const bf16x8*>(&As[(wv * 16 + m16) * 72 + quad * 8 + kk]);
#pragma unroll
      for (int ct = 0; ct < 4; ct++) {
        bf16x8 b = *reinterpret_cast<const bf16x8*>(&Ws[(ct * 16 + m16) * 72 + quad * 8 + kk]);
        acc[ct] = __builtin_amdgcn_mfma_f32_16x16x32_bf16(a, b, acc[ct], 0, 0, 0);
      }
    }
  }

  float bn[4];
#pragma unroll
  for (int ct = 0; ct < 4; ct++) bn[ct] = bias[n0 + ct * 16 + m16];
#pragma unroll
  for (int ct = 0; ct < 4; ct++) {
    int n = n0 + ct * 16 + m16;
#pragma unroll
    for (int r = 0; r < 4; r++) {
      int m = m0 + wv * 16 + quad * 4 + r;
      Cout[(size_t)m * DM + n] = acc[ct][r] + bn[ct];
    }
  }
}

// ---------------------------------------------------------------------------
// exp2 + mask + pack one q-subtile's scores into the two PV A-fragments.
// Mask bit for C slot (ct,r): true key = 32(ct&1) + 16(r>>1) + 8(r&1)
// + 2*quad + (ct>>1); lo/hi are the lane's mask word pre-shifted by 2*quad.
__device__ __forceinline__ void pack_p(const f32x4* s, u32 lo, u32 hi,
                                       uint4& o0, uint4& o1) {
  u32 pk[8];
#pragma unroll
  for (int ct = 0; ct < 4; ct++) {
    u32 w = (ct & 1) ? hi : lo;
    int b = ct >> 1;
    float p0 = __builtin_amdgcn_exp2f(((w >> b) & 1u)        ? -1e9f : s[ct][0]);
    float p1 = __builtin_amdgcn_exp2f(((w >> (b + 8)) & 1u)  ? -1e9f : s[ct][1]);
    float p2 = __builtin_amdgcn_exp2f(((w >> (b + 16)) & 1u) ? -1e9f : s[ct][2]);
    float p3 = __builtin_amdgcn_exp2f(((w >> (b + 24)) & 1u) ? -1e9f : s[ct][3]);
    pk[2 * ct]     = __builtin_amdgcn_perm(__float_as_uint(p1) + 0x8000u,
                                           __float_as_uint(p0) + 0x8000u, 0x07060302u);
    pk[2 * ct + 1] = __builtin_amdgcn_perm(__float_as_uint(p3) + 0x8000u,
                                           __float_as_uint(p2) + 0x8000u, 0x07060302u);
  }
  o0 = make_uint4(pk[0], pk[1], pk[2], pk[3]);
  o1 = make_uint4(pk[4], pk[5], pk[6], pk[7]);
}

// ---------------------------------------------------------------------------
// Flash attention v3.1: fixed-shift softmax, grid split-K x8, NO P roundtrip.
// Key axis co-permuted in K staging (sigma bit-shuffle) and V4 layout so the
// S^T C-layout registers, exp2'd and bf16-packed, ARE the PV A-fragments.
// Each wave owns 32 q (2 subtiles); block 256 thr = 128 q; grid (32, 8, 8)
// = 2048 blocks = 8 blocks/CU -> 32 waves/CU co-resident.
__global__ __launch_bounds__(256, 8) void attn_mfma(
    const u16* __restrict__ Q, const u16* __restrict__ K,
    const u16* __restrict__ V4, const u64* __restrict__ mbits,
    u16* __restrict__ Op, float* __restrict__ Lp) {
  __shared__ u16 Ks[64 * 72];
  __shared__ u16 Vs[64 * 72];

  const int t = threadIdx.x;
  const int lane = t & 63, w4 = t >> 6;
  const int m16 = lane & 15, quad = lane >> 4;
  const int q0 = blockIdx.x * 128;
  const int h = blockIdx.y;
  const int g = blockIdx.z;          // key eighth: 512 keys, 8 tiles
  const size_t hoff = (size_t)h * S_LEN * DK;
  const size_t kbase = hoff + (size_t)g * 512 * DK;

  // Q fragments for the wave's two q-subtiles (pre-scaled in Q-GEMM)
  const u16* qpA = Q + hoff + (size_t)(q0 + w4 * 32 + m16) * DK + quad * 8;
  bf16x8 qloA = *reinterpret_cast<const bf16x8*>(qpA);
  bf16x8 qhiA = *reinterpret_cast<const bf16x8*>(qpA + 32);
  bf16x8 qloB = *reinterpret_cast<const bf16x8*>(qpA + 16 * DK);
  bf16x8 qhiB = *reinterpret_cast<const bf16x8*>(qpA + 16 * DK + 32);

  union { u16 u[8]; bf16x8 v; } onesu;
#pragma unroll
  for (int j = 0; j < 8; j++) onesu.u[j] = 0x3F80;
  const bf16x8 ones = onesu.v;

  f32x4 accA[4], accB[4];
  f32x4 acc_lA = (f32x4)0.f, acc_lB = (f32x4)0.f;
#pragma unroll
  for (int dt = 0; dt < 4; dt++) { accA[dt] = (f32x4)0.f; accB[dt] = (f32x4)0.f; }

  for (int k0 = 0; k0 < 512; k0 += 64) {
    const int kg = g * 512 + k0;
    // stage K rows at sigma(rg) = [k0,k5,k2,k1,k4,k3]; V4 already slot-ordered
#pragma unroll
    for (int c0 = 0; c0 < 2; c0++) {
      int c = t + c0 * 256;
      int rg = c >> 3, cc = c & 7;
      int sr = ((rg & 1) << 5) | (((rg >> 5) & 1) << 4) | (((rg >> 2) & 1) << 3) |
               (((rg >> 1) & 1) << 2) | (((rg >> 4) & 1) << 1) | ((rg >> 3) & 1);
      *reinterpret_cast<uint4*>(&Ks[sr * 72 + cc * 8]) =
          *reinterpret_cast<const uint4*>(&K[kbase + (size_t)(k0 + rg) * DK + cc * 8]);
      *reinterpret_cast<uint4*>(&Vs[rg * 72 + cc * 8]) =
          *reinterpret_cast<const uint4*>(&V4[(size_t)(h * 64 + rg) * 4096 + kg + cc * 8]);
    }
    u64 mqA = mbits[(size_t)(q0 + w4 * 32 + m16) * 64 + (kg >> 6)] >> (2 * quad);
    u64 mqB = mbits[(size_t)(q0 + w4 * 32 + 16 + m16) * 64 + (kg >> 6)] >> (2 * quad);
    __syncthreads();   // tiles ready

    // S^T - FMAX for both q-subtiles; each K fragment feeds 2 MFMAs
    f32x4 sA[4], sB[4];
#pragma unroll
    for (int ct = 0; ct < 4; ct++) { sA[ct] = (f32x4)(-FMAX); sB[ct] = (f32x4)(-FMAX); }
#pragma unroll
    for (int ct = 0; ct < 4; ct++) {
      bf16x8 klo = *reinterpret_cast<const bf16x8*>(&Ks[(ct * 16 + m16) * 72 + quad * 8]);
      bf16x8 khi = *reinterpret_cast<const bf16x8*>(&Ks[(ct * 16 + m16) * 72 + quad * 8 + 32]);
      sA[ct] = __builtin_amdgcn_mfma_f32_16x16x32_bf16(klo, qloA, sA[ct], 0, 0, 0);
      sA[ct] = __builtin_amdgcn_mfma_f32_16x16x32_bf16(khi, qhiA, sA[ct], 0, 0, 0);
      sB[ct] = __builtin_amdgcn_mfma_f32_16x16x32_bf16(klo, qloB, sB[ct], 0, 0, 0);
      sB[ct] = __builtin_amdgcn_mfma_f32_16x16x32_bf16(khi, qhiB, sB[ct], 0, 0, 0);
    }

    // exp2 + pack: registers become the PV A-fragments directly (no LDS)
    union { uint4 i; bf16x8 v; } pA0, pA1, pB0, pB1;
    pack_p(sA, (u32)mqA, (u32)(mqA >> 32), pA0.i, pA1.i);
    pack_p(sB, (u32)mqB, (u32)(mqB >> 32), pB0.i, pB1.i);

    // O += P @ V ; l += P @ 1; each V fragment feeds 2 MFMAs
#pragma unroll
    for (int dt = 0; dt < 4; dt++) {
      bf16x8 vlo = *reinterpret_cast<const bf16x8*>(&Vs[(dt * 16 + m16) * 72 + quad * 8]);
      bf16x8 vhi = *reinterpret_cast<const bf16x8*>(&Vs[(dt * 16 + m16) * 72 + quad * 8 + 32]);
      accA[dt] = __builtin_amdgcn_mfma_f32_16x16x32_bf16(pA0.v, vlo, accA[dt], 0, 0, 0);
      accA[dt] = __builtin_amdgcn_mfma_f32_16x16x32_bf16(pA1.v, vhi, accA[dt], 0, 0, 0);
      accB[dt] = __builtin_amdgcn_mfma_f32_16x16x32_bf16(pB0.v, vlo, accB[dt], 0, 0, 0);
      accB[dt] = __builtin_amdgcn_mfma_f32_16x16x32_bf16(pB1.v, vhi, accB[dt], 0, 0, 0);
    }
    acc_lA = __builtin_amdgcn_mfma_f32_16x16x32_bf16(pA0.v, ones, acc_lA, 0, 0, 0);
    acc_lA = __builtin_amdgcn_mfma_f32_16x16x32_bf16(pA1.v, ones, acc_lA, 0, 0, 0);
    acc_lB = __builtin_amdgcn_mfma_f32_16x16x32_bf16(pB0.v, ones, acc_lB, 0, 0, 0);
    acc_lB = __builtin_amdgcn_mfma_f32_16x16x32_bf16(pB1.v, ones, acc_lB, 0, 0, 0);
    __syncthreads();   // all tile reads done before next staging
  }

  // partial O (unnormalized bf16) + partial l (f32)
  u16* Og = Op + (size_t)g * 2097152;
#pragma unroll
  for (int dt = 0; dt < 4; dt++)
#pragma unroll
    for (int r = 0; r < 4; r++) {
      Og[(size_t)(q0 + w4 * 32 + quad * 4 + r) * DM + h * DK + dt * 16 + m16] =
          f2bf(accA[dt][r]);
      Og[(size_t)(q0 + w4 * 32 + 16 + quad * 4 + r) * DM + h * DK + dt * 16 + m16] =
          f2bf(accB[dt][r]);
    }
  if (m16 == 0) {
#pragma unroll
    for (int r = 0; r < 4; r++) {
      Lp[g * 32768 + h * 4096 + q0 + w4 * 32 + quad * 4 + r] = acc_lA[r];
      Lp[g * 32768 + h * 4096 + q0 + w4 * 32 + 16 + quad * 4 + r] = acc_lB[r];
    }
  }
}

// ---------------------------------------------------------------------------
// Merge the eight key-split partials: Out = sum(O_g) / sum(l_g). bf16 out.
__global__ __launch_bounds__(256) void attn_merge(
    const u16* __restrict__ Op, const float* __restrict__ Lp,
    u16* __restrict__ Out) {
  int i8 = (blockIdx.x * 256 + threadIdx.x) * 8;   // 8 elems/thread, same (q,h)
  int q = i8 >> 9;
  int h = (i8 >> 6) & 7;
  float l = 0.f;
#pragma unroll
  for (int part = 0; part < 8; part++) l += Lp[part * 32768 + h * 4096 + q];
  float rl = 1.f / l;
  float o[8];
#pragma unroll
  for (int j = 0; j < 8; j++) o[j] = 0.f;
#pragma unroll
  for (int part = 0; part < 8; part++) {
    ushort4 v0 = *reinterpret_cast<const ushort4*>(Op + part * 2097152 + i8);
    ushort4 v1 = *reinterpret_cast<const ushort4*>(Op + part * 2097152 + i8 + 4);
    o[0] += bf2f(v0.x); o[1] += bf2f(v0.y); o[2] += bf2f(v0.z); o[3] += bf2f(v0.w);
    o[4] += bf2f(v1.x); o[5] += bf2f(v1.y); o[6] += bf2f(v1.z); o[7] += bf2f(v1.w);
  }
  ushort4 o0 = make_ushort4(f2bf(o[0] * rl), f2bf(o[1] * rl),
                            f2bf(o[2] * rl), f2bf(o[3] * rl));
  ushort4 o1 = make_ushort4(f2bf(o[4] * rl), f2bf(o[5] * rl),
                            f2bf(o[6] * rl), f2bf(o[7] * rl));
  *reinterpret_cast<ushort4*>(Out + i8) = o0;
  *reinterpret_cast<ushort4*>(Out + i8 + 4) = o1;
}

// ---------------------------------------------------------------------------
extern "C" void kernel_launch(void* const* d_in, const int* in_sizes, int n_in,
                              void* d_out, int out_size, void* d_ws, size_t ws_size,
                              hipStream_t stream) {
  const float* x    = (const float*)d_in[0];
  const int*   mask = (const int*)d_in[1];
  const float* wq_w = (const float*)d_in[2];
  const float* wq_b = (const float*)d_in[3];
  const float* wk_w = (const float*)d_in[4];
  const float* wk_b = (const float*)d_in[5];
  const float* wv_w = (const float*)d_in[6];
  const float* wv_b = (const float*)d_in[7];
  const float* dw   = (const float*)d_in[8];
  const float* db   = (const float*)d_in[9];

  // ws (u16 elems): xb 2M | wcat 768K | dwb 256K | Qb/Kb/V4 2M each |
  // Opart 8x2M | mb 256K u64 | Lp 256K f32.  ~53 MB total (ws is ~256 MB).
  u16* xb    = (u16*)d_ws;
  u16* wcat  = xb    + 2097152;
  u16* dwb   = wcat  + 786432;
  u16* Qb    = dwb   + 262144;
  u16* Kb    = Qb    + 2097152;
  u16* V4    = Kb    + 2097152;
  u16* Opart = V4    + 2097152;
  u64* mb    = (u64*)(Opart + 8 * 2097152);
  float* Lp  = (float*)(mb + 262144);

  prep<<<68608, 256, 0, stream>>>(mask, mb, x, wq_w, wk_w, wv_w, dw,
                                  xb, wcat, dwb);

  qkv_gemm<<<dim3(12, 64), 256, 0, stream>>>(xb, wcat, wq_b, wk_b, wv_b,
                                             Qb, Kb, V4);

  attn_mfma<<<dim3(32, NH, 8), 256, 0, stream>>>(Qb, Kb, V4, mb, Opart, Lp);
  attn_merge<<<1024, 256, 0, stream>>>(Opart, Lp, Qb);

  dense_gemm<<<dim3(8, 64), 256, 0, stream>>>(Qb, dwb, db, (float*)d_out);
}

// Round 14
// 446.877 us; speedup vs baseline: 1.1495x; 1.1495x over previous
//
#include <hip/hip_runtime.h>
#include <hip/hip_bf16.h>

#define S_LEN 4096
#define DM    512
#define NH    8
#define DK    64

typedef __attribute__((ext_vector_type(8))) __bf16 bf16x8;
typedef __attribute__((ext_vector_type(4))) float  f32x4;
typedef unsigned short u16;
typedef unsigned int   u32;
typedef unsigned long long u64;

// Q-GEMM epilogue scale: 1/sqrt(64) * log2(e)  (softmax in log2 domain)
#define SQ_SCALE (0.125f * 1.44269504f)
// Fixed softmax shift (log2-domain). Shift-invariant; l-division restores scale.
#define FMAX 12.0f

__device__ __forceinline__ u16 f2bf(float f) {
  union { float f; u32 i; } v; v.f = f;
  u32 r = v.i + 0x7fff + ((v.i >> 16) & 1);   // RNE
  return (u16)(r >> 16);
}
__device__ __forceinline__ float bf2f(u16 u) {
  union { u32 i; float f; } v; v.i = ((u32)u) << 16; return v.f;
}

// ---------------------------------------------------------------------------
// Fused prep: blocks [0,65536) pack mask int32 -> u64 bitmask;
// blocks [65536,68608) convert fp32 -> bf16 (x | wq|wk|wv -> wcat | dw).
__global__ __launch_bounds__(256) void prep(
    const int* __restrict__ mask, u64* __restrict__ mb,
    const float* __restrict__ x, const float* __restrict__ wq,
    const float* __restrict__ wk, const float* __restrict__ wv,
    const float* __restrict__ dw,
    u16* __restrict__ xb, u16* __restrict__ wcat, u16* __restrict__ dwb) {
  int b = blockIdx.x;
  if (b < 65536) {
    int gid = b * 256 + threadIdx.x;
    u64 bb = __ballot(mask[gid] != 0);
    if ((threadIdx.x & 63) == 0) mb[gid >> 6] = bb;
  } else {
    b -= 65536;
    const float* src; u16* dst; size_t off;
    if      (b < 2048) { src = x;  dst = xb;   off = (size_t)b * 1024; }
    else if (b < 2304) { src = wq; dst = wcat; off = (size_t)(b - 2048) * 1024; }
    else if (b < 2560) { src = wk; dst = wcat + 262144; off = (size_t)(b - 2304) * 1024; }
    else if (b < 2816) { src = wv; dst = wcat + 524288; off = (size_t)(b - 2560) * 1024; }
    else               { src = dw; dst = dwb;  off = (size_t)(b - 2816) * 1024; }
    size_t i = off + (size_t)threadIdx.x * 4;
    float4 v = *reinterpret_cast<const float4*>(src + i);
    ushort4 o = make_ushort4(f2bf(v.x), f2bf(v.y), f2bf(v.z), f2bf(v.w));
    *reinterpret_cast<ushort4*>(dst + i) = o;
  }
}

// ---------------------------------------------------------------------------
// Fused QKV projection, 64(m) x 128(n) tiles: C[4096,1536] = x @ Wcat^T + bias.
// grid (12, 64). seg 0=Q (scaled), 1=K, 2=V.
// V output layout V4[(h*64+d)][tile*64 + slot] where for true key kappa =
// m'*8+c (from _split_heads: h=m>>9, d=n&63, key=(m&511)*8+(n>>6)):
// tile = m'>>3, slot = (c&1)*32 + (c>>1)*8 + (m'&7).  This slot order makes
// attn's P C-layout directly usable as the PV A-fragment (see attn_mfma).
__global__ __launch_bounds__(256) void qkv_gemm(
    const u16* __restrict__ A, const u16* __restrict__ Wcat,
    const float* __restrict__ bq, const float* __restrict__ bk,
    const float* __restrict__ bv,
    u16* __restrict__ Qb, u16* __restrict__ Kb, u16* __restrict__ V4) {
  __shared__ u16 As[64 * 72];    // 9.2 KB
  __shared__ u16 Ws[128 * 72];   // 18.4 KB (reused as T in V epilogue)
  const int t = threadIdx.x;
  const int lane = t & 63, wv = t >> 6;
  const int m16 = lane & 15, quad = lane >> 4;
  const int n0g = blockIdx.x * 128, m0 = blockIdx.y * 64;
  const int seg = n0g >> 9;
  const int n0 = n0g & 511;
  const int mq = wv >> 1, nq = wv & 1;   // wave quadrant

  f32x4 acc[2][4];
#pragma unroll
  for (int i = 0; i < 2; i++)
#pragma unroll
    for (int j = 0; j < 4; j++) acc[i][j] = (f32x4)0.f;

  for (int k0 = 0; k0 < DM; k0 += 64) {
    __syncthreads();
#pragma unroll
    for (int c0 = 0; c0 < 2; c0++) {       // A: 64x64 = 512 uint4
      int c = t + c0 * 256;
      int row = c >> 3, col = (c & 7) * 8;
      *reinterpret_cast<uint4*>(&As[row * 72 + col]) =
          *reinterpret_cast<const uint4*>(&A[(size_t)(m0 + row) * DM + k0 + col]);
    }
#pragma unroll
    for (int c0 = 0; c0 < 4; c0++) {       // W: 128x64 = 1024 uint4
      int c = t + c0 * 256;
      int row = c >> 3, col = (c & 7) * 8;
      *reinterpret_cast<uint4*>(&Ws[row * 72 + col]) =
          *reinterpret_cast<const uint4*>(&Wcat[(size_t)(n0g + row) * DM + k0 + col]);
    }
    __syncthreads();
#pragma unroll
    for (int kk = 0; kk < 64; kk += 32) {
      bf16x8 a0 = *reinterpret_cast<const bf16x8*>(&As[(mq * 32 + m16) * 72 + quad * 8 + kk]);
      bf16x8 a1 = *reinterpret_cast<const bf16x8*>(&As[(mq * 32 + 16 + m16) * 72 + quad * 8 + kk]);
#pragma unroll
      for (int ct = 0; ct < 4; ct++) {
        bf16x8 b = *reinterpret_cast<const bf16x8*>(&Ws[(nq * 64 + ct * 16 + m16) * 72 + quad * 8 + kk]);
        acc[0][ct] = __builtin_amdgcn_mfma_f32_16x16x32_bf16(a0, b, acc[0][ct], 0, 0, 0);
        acc[1][ct] = __builtin_amdgcn_mfma_f32_16x16x32_bf16(a1, b, acc[1][ct], 0, 0, 0);
      }
    }
  }

  const float* bias = (seg == 0) ? bq : (seg == 1) ? bk : bv;
  const float scale = (seg == 0) ? SQ_SCALE : 1.f;
  float bn[4];
#pragma unroll
  for (int ct = 0; ct < 4; ct++) bn[ct] = bias[n0 + nq * 64 + ct * 16 + m16];

  if (seg == 2) {
    // transpose through LDS (reuse Ws as T[128 nl][64 ml], stride 72)
    __syncthreads();   // all fragment reads of Ws done
    u16* T = Ws;
#pragma unroll
    for (int rt = 0; rt < 2; rt++)
#pragma unroll
      for (int ct = 0; ct < 4; ct++)
#pragma unroll
        for (int r = 0; r < 4; r++)
          T[(nq * 64 + ct * 16 + m16) * 72 + mq * 32 + rt * 16 + quad * 4 + r] =
              f2bf(acc[rt][ct][r] + bn[ct]);
    __syncthreads();
    const int h    = m0 >> 9;
    const int mp   = m0 & 511;   // multiple of 64
    const int cseg = n0 >> 7;    // 0..3
#pragma unroll
    for (int c0 = 0; c0 < 4; c0++) {       // 1024 uint4 copies
      int c = t + c0 * 256;
      int d  = c >> 4;          // 0..63
      int tl = (c >> 1) & 7;    // 0..7
      int cl = c & 1;           // 0..1
      uint4 v = *reinterpret_cast<const uint4*>(&T[(cl * 64 + d) * 72 + tl * 8]);
      *reinterpret_cast<uint4*>(
          &V4[(size_t)(h * 64 + d) * 4096 + ((mp >> 3) + tl) * 64 + cl * 32 + cseg * 8]) = v;
    }
  } else {
    u16* dst = (seg == 0) ? Qb : Kb;
#pragma unroll
    for (int rt = 0; rt < 2; rt++)
#pragma unroll
      for (int ct = 0; ct < 4; ct++) {
        int n = n0 + nq * 64 + ct * 16 + m16;
#pragma unroll
        for (int r = 0; r < 4; r++) {
          int m = m0 + mq * 32 + rt * 16 + quad * 4 + r;
          dst[(size_t)m * DM + n] = f2bf((acc[rt][ct][r] + bn[ct]) * scale);
        }
      }
  }
}

// ---------------------------------------------------------------------------
// Dense out-proj, 64x64 tiles: C[4096,512](f32) = A @ dw^T + db. grid (8,64).
__global__ __launch_bounds__(256) void dense_gemm(
    const u16* __restrict__ A, const u16* __restrict__ W,
    const float* __restrict__ bias, float* __restrict__ Cout) {
  __shared__ u16 As[64 * 72];
  __shared__ u16 Ws[64 * 72];
  const int t = threadIdx.x;
  const int lane = t & 63, wv = t >> 6;
  const int m16 = lane & 15, quad = lane >> 4;
  const int n0 = blockIdx.x * 64, m0 = blockIdx.y * 64;

  f32x4 acc[4];
#pragma unroll
  for (int j = 0; j < 4; j++) acc[j] = (f32x4)0.f;

  for (int k0 = 0; k0 < DM; k0 += 64) {
    __syncthreads();
#pragma unroll
    for (int c0 = 0; c0 < 2; c0++) {
      int c = t + c0 * 256;
      int row = c >> 3, col = (c & 7) * 8;
      *reinterpret_cast<uint4*>(&As[row * 72 + col]) =
          *reinterpret_cast<const uint4*>(&A[(size_t)(m0 + row) * DM + k0 + col]);
      *reinterpret_cast<uint4*>(&Ws[row * 72 + col]) =
          *reinterpret_cast<const uint4*>(&W[(size_t)(n0 + row) * DM + k0 + col]);
    }
    __syncthreads();
#pragma unroll
    for (int kk = 0; kk < 64; kk += 32) {
      bf16x8 a = *reinterpret_cast<const bf16x8*>(&As[(wv * 16 + m16) * 72 + quad * 8 + kk]);
#pragma unroll
      for (int ct = 0; ct < 4; ct++) {
        bf16x8 b = *reinterpret_cast<const bf16x8*>(&Ws[(ct * 16 + m16) * 72 + quad * 8 + kk]);
        acc[ct] = __builtin_amdgcn_mfma_f32_16x16x32_bf16(a, b, acc[ct], 0, 0, 0);
      }
    }
  }

  float bn[4];
#pragma unroll
  for (int ct = 0; ct < 4; ct++) bn[ct] = bias[n0 + ct * 16 + m16];
#pragma unroll
  for (int ct = 0; ct < 4; ct++) {
    int n = n0 + ct * 16 + m16;
#pragma unroll
    for (int r = 0; r < 4; r++) {
      int m = m0 + wv * 16 + quad * 4 + r;
      Cout[(size_t)m * DM + n] = acc[ct][r] + bn[ct];
    }
  }
}

// ---------------------------------------------------------------------------
// exp2 + mask + pack one q-subtile's scores into the two PV A-fragments.
// Mask bit for C slot (ct,r): true key = 32(ct&1) + 16(r>>1) + 8(r&1)
// + 2*quad + (ct>>1); lo/hi are the lane's mask word pre-shifted by 2*quad.
__device__ __forceinline__ void pack_p(const f32x4* s, u32 lo, u32 hi,
                                       uint4& o0, uint4& o1) {
  u32 pk[8];
#pragma unroll
  for (int ct = 0; ct < 4; ct++) {
    u32 w = (ct & 1) ? hi : lo;
    int b = ct >> 1;
    float p0 = __builtin_amdgcn_exp2f(((w >> b) & 1u)        ? -1e9f : s[ct][0]);
    float p1 = __builtin_amdgcn_exp2f(((w >> (b + 8)) & 1u)  ? -1e9f : s[ct][1]);
    float p2 = __builtin_amdgcn_exp2f(((w >> (b + 16)) & 1u) ? -1e9f : s[ct][2]);
    float p3 = __builtin_amdgcn_exp2f(((w >> (b + 24)) & 1u) ? -1e9f : s[ct][3]);
    pk[2 * ct]     = __builtin_amdgcn_perm(__float_as_uint(p1) + 0x8000u,
                                           __float_as_uint(p0) + 0x8000u, 0x07060302u);
    pk[2 * ct + 1] = __builtin_amdgcn_perm(__float_as_uint(p3) + 0x8000u,
                                           __float_as_uint(p2) + 0x8000u, 0x07060302u);
  }
  o0 = make_uint4(pk[0], pk[1], pk[2], pk[3]);
  o1 = make_uint4(pk[4], pk[5], pk[6], pk[7]);
}

// ---------------------------------------------------------------------------
// Flash attention v3.2: fixed-shift softmax, grid split-K x8, NO P roundtrip.
// Key axis co-permuted in K staging (sigma bit-shuffle) and V4 layout so the
// S^T C-layout registers, exp2'd and bf16-packed, ARE the PV A-fragments.
// Each wave owns 32 q (2 subtiles); block 256 thr = 128 q; grid (32, 8, 8)
// = 2048 blocks = 8 blocks/CU.
// launch_bounds min-waves = 6 (NOT 8): the kernel needs ~64 VGPRs; asking for
// 8 waves/EU made the allocator target 32 VGPRs -> massive scratch spill
// (round 13: 1.65 GB HBM traffic/dispatch). 512/6 = 85-VGPR cap keeps the
// round-12 spill-free allocation while still allowing 6+ blocks/CU.
__global__ __launch_bounds__(256, 6) void attn_mfma(
    const u16* __restrict__ Q, const u16* __restrict__ K,
    const u16* __restrict__ V4, const u64* __restrict__ mbits,
    u16* __restrict__ Op, float* __restrict__ Lp) {
  __shared__ u16 Ks[64 * 72];
  __shared__ u16 Vs[64 * 72];

  const int t = threadIdx.x;
  const int lane = t & 63, w4 = t >> 6;
  const int m16 = lane & 15, quad = lane >> 4;
  const int q0 = blockIdx.x * 128;
  const int h = blockIdx.y;
  const int g = blockIdx.z;          // key eighth: 512 keys, 8 tiles
  const size_t hoff = (size_t)h * S_LEN * DK;
  const size_t kbase = hoff + (size_t)g * 512 * DK;

  // Q fragments for the wave's two q-subtiles (pre-scaled in Q-GEMM)
  const u16* qpA = Q + hoff + (size_t)(q0 + w4 * 32 + m16) * DK + quad * 8;
  bf16x8 qloA = *reinterpret_cast<const bf16x8*>(qpA);
  bf16x8 qhiA = *reinterpret_cast<const bf16x8*>(qpA + 32);
  bf16x8 qloB = *reinterpret_cast<const bf16x8*>(qpA + 16 * DK);
  bf16x8 qhiB = *reinterpret_cast<const bf16x8*>(qpA + 16 * DK + 32);

  union { u16 u[8]; bf16x8 v; } onesu;
#pragma unroll
  for (int j = 0; j < 8; j++) onesu.u[j] = 0x3F80;
  const bf16x8 ones = onesu.v;

  f32x4 accA[4], accB[4];
  f32x4 acc_lA = (f32x4)0.f, acc_lB = (f32x4)0.f;
#pragma unroll
  for (int dt = 0; dt < 4; dt++) { accA[dt] = (f32x4)0.f; accB[dt] = (f32x4)0.f; }

  for (int k0 = 0; k0 < 512; k0 += 64) {
    const int kg = g * 512 + k0;
    // stage K rows at sigma(rg) = [k0,k5,k2,k1,k4,k3]; V4 already slot-ordered
#pragma unroll
    for (int c0 = 0; c0 < 2; c0++) {
      int c = t + c0 * 256;
      int rg = c >> 3, cc = c & 7;
      int sr = ((rg & 1) << 5) | (((rg >> 5) & 1) << 4) | (((rg >> 2) & 1) << 3) |
               (((rg >> 1) & 1) << 2) | (((rg >> 4) & 1) << 1) | ((rg >> 3) & 1);
      *reinterpret_cast<uint4*>(&Ks[sr * 72 + cc * 8]) =
          *reinterpret_cast<const uint4*>(&K[kbase + (size_t)(k0 + rg) * DK + cc * 8]);
      *reinterpret_cast<uint4*>(&Vs[rg * 72 + cc * 8]) =
          *reinterpret_cast<const uint4*>(&V4[(size_t)(h * 64 + rg) * 4096 + kg + cc * 8]);
    }
    u64 mqA = mbits[(size_t)(q0 + w4 * 32 + m16) * 64 + (kg >> 6)] >> (2 * quad);
    u64 mqB = mbits[(size_t)(q0 + w4 * 32 + 16 + m16) * 64 + (kg >> 6)] >> (2 * quad);
    __syncthreads();   // tiles ready

    // S^T - FMAX for both q-subtiles; each K fragment feeds 2 MFMAs
    f32x4 sA[4], sB[4];
#pragma unroll
    for (int ct = 0; ct < 4; ct++) { sA[ct] = (f32x4)(-FMAX); sB[ct] = (f32x4)(-FMAX); }
#pragma unroll
    for (int ct = 0; ct < 4; ct++) {
      bf16x8 klo = *reinterpret_cast<const bf16x8*>(&Ks[(ct * 16 + m16) * 72 + quad * 8]);
      bf16x8 khi = *reinterpret_cast<const bf16x8*>(&Ks[(ct * 16 + m16) * 72 + quad * 8 + 32]);
      sA[ct] = __builtin_amdgcn_mfma_f32_16x16x32_bf16(klo, qloA, sA[ct], 0, 0, 0);
      sA[ct] = __builtin_amdgcn_mfma_f32_16x16x32_bf16(khi, qhiA, sA[ct], 0, 0, 0);
      sB[ct] = __builtin_amdgcn_mfma_f32_16x16x32_bf16(klo, qloB, sB[ct], 0, 0, 0);
      sB[ct] = __builtin_amdgcn_mfma_f32_16x16x32_bf16(khi, qhiB, sB[ct], 0, 0, 0);
    }

    // exp2 + pack: registers become the PV A-fragments directly (no LDS)
    union { uint4 i; bf16x8 v; } pA0, pA1, pB0, pB1;
    pack_p(sA, (u32)mqA, (u32)(mqA >> 32), pA0.i, pA1.i);
    pack_p(sB, (u32)mqB, (u32)(mqB >> 32), pB0.i, pB1.i);

    // O += P @ V ; l += P @ 1; each V fragment feeds 2 MFMAs
#pragma unroll
    for (int dt = 0; dt < 4; dt++) {
      bf16x8 vlo = *reinterpret_cast<const bf16x8*>(&Vs[(dt * 16 + m16) * 72 + quad * 8]);
      bf16x8 vhi = *reinterpret_cast<const bf16x8*>(&Vs[(dt * 16 + m16) * 72 + quad * 8 + 32]);
      accA[dt] = __builtin_amdgcn_mfma_f32_16x16x32_bf16(pA0.v, vlo, accA[dt], 0, 0, 0);
      accA[dt] = __builtin_amdgcn_mfma_f32_16x16x32_bf16(pA1.v, vhi, accA[dt], 0, 0, 0);
      accB[dt] = __builtin_amdgcn_mfma_f32_16x16x32_bf16(pB0.v, vlo, accB[dt], 0, 0, 0);
      accB[dt] = __builtin_amdgcn_mfma_f32_16x16x32_bf16(pB1.v, vhi, accB[dt], 0, 0, 0);
    }
    acc_lA = __builtin_amdgcn_mfma_f32_16x16x32_bf16(pA0.v, ones, acc_lA, 0, 0, 0);
    acc_lA = __builtin_amdgcn_mfma_f32_16x16x32_bf16(pA1.v, ones, acc_lA, 0, 0, 0);
    acc_lB = __builtin_amdgcn_mfma_f32_16x16x32_bf16(pB0.v, ones, acc_lB, 0, 0, 0);
    acc_lB = __builtin_amdgcn_mfma_f32_16x16x32_bf16(pB1.v, ones, acc_lB, 0, 0, 0);
    __syncthreads();   // all tile reads done before next staging
  }

  // partial O (unnormalized bf16) + partial l (f32)
  u16* Og = Op + (size_t)g * 2097152;
#pragma unroll
  for (int dt = 0; dt < 4; dt++)
#pragma unroll
    for (int r = 0; r < 4; r++) {
      Og[(size_t)(q0 + w4 * 32 + quad * 4 + r) * DM + h * DK + dt * 16 + m16] =
          f2bf(accA[dt][r]);
      Og[(size_t)(q0 + w4 * 32 + 16 + quad * 4 + r) * DM + h * DK + dt * 16 + m16] =
          f2bf(accB[dt][r]);
    }
  if (m16 == 0) {
#pragma unroll
    for (int r = 0; r < 4; r++) {
      Lp[g * 32768 + h * 4096 + q0 + w4 * 32 + quad * 4 + r] = acc_lA[r];
      Lp[g * 32768 + h * 4096 + q0 + w4 * 32 + 16 + quad * 4 + r] = acc_lB[r];
    }
  }
}

// ---------------------------------------------------------------------------
// Merge the eight key-split partials: Out = sum(O_g) / sum(l_g). bf16 out.
__global__ __launch_bounds__(256) void attn_merge(
    const u16* __restrict__ Op, const float* __restrict__ Lp,
    u16* __restrict__ Out) {
  int i8 = (blockIdx.x * 256 + threadIdx.x) * 8;   // 8 elems/thread, same (q,h)
  int q = i8 >> 9;
  int h = (i8 >> 6) & 7;
  float l = 0.f;
#pragma unroll
  for (int part = 0; part < 8; part++) l += Lp[part * 32768 + h * 4096 + q];
  float rl = 1.f / l;
  float o[8];
#pragma unroll
  for (int j = 0; j < 8; j++) o[j] = 0.f;
#pragma unroll
  for (int part = 0; part < 8; part++) {
    ushort4 v0 = *reinterpret_cast<const ushort4*>(Op + part * 2097152 + i8);
    ushort4 v1 = *reinterpret_cast<const ushort4*>(Op + part * 2097152 + i8 + 4);
    o[0] += bf2f(v0.x); o[1] += bf2f(v0.y); o[2] += bf2f(v0.z); o[3] += bf2f(v0.w);
    o[4] += bf2f(v1.x); o[5] += bf2f(v1.y); o[6] += bf2f(v1.z); o[7] += bf2f(v1.w);
  }
  ushort4 o0 = make_ushort4(f2bf(o[0] * rl), f2bf(o[1] * rl),
                            f2bf(o[2] * rl), f2bf(o[3] * rl));
  ushort4 o1 = make_ushort4(f2bf(o[4] * rl), f2bf(o[5] * rl),
                            f2bf(o[6] * rl), f2bf(o[7] * rl));
  *reinterpret_cast<ushort4*>(Out + i8) = o0;
  *reinterpret_cast<ushort4*>(Out + i8 + 4) = o1;
}

// ---------------------------------------------------------------------------
extern "C" void kernel_launch(void* const* d_in, const int* in_sizes, int n_in,
                              void* d_out, int out_size, void* d_ws, size_t ws_size,
                              hipStream_t stream) {
  const float* x    = (const float*)d_in[0];
  const int*   mask = (const int*)d_in[1];
  const float* wq_w = (const float*)d_in[2];
  const float* wq_b = (const float*)d_in[3];
  const float* wk_w = (const float*)d_in[4];
  const float* wk_b = (const float*)d_in[5];
  const float* wv_w = (const float*)d_in[6];
  const float* wv_b = (const float*)d_in[7];
  const float* dw   = (const float*)d_in[8];
  const float* db   = (const float*)d_in[9];

  // ws (u16 elems): xb 2M | wcat 768K | dwb 256K | Qb/Kb/V4 2M each |
  // Opart 8x2M | mb 256K u64 | Lp 256K f32.  ~53 MB total (ws is ~256 MB).
  u16* xb    = (u16*)d_ws;
  u16* wcat  = xb    + 2097152;
  u16* dwb   = wcat  + 786432;
  u16* Qb    = dwb   + 262144;
  u16* Kb    = Qb    + 2097152;
  u16* V4    = Kb    + 2097152;
  u16* Opart = V4    + 2097152;
  u64* mb    = (u64*)(Opart + 8 * 2097152);
  float* Lp  = (float*)(mb + 262144);

  prep<<<68608, 256, 0, stream>>>(mask, mb, x, wq_w, wk_w, wv_w, dw,
                                  xb, wcat, dwb);

  qkv_gemm<<<dim3(12, 64), 256, 0, stream>>>(xb, wcat, wq_b, wk_b, wv_b,
                                             Qb, Kb, V4);

  attn_mfma<<<dim3(32, NH, 8), 256, 0, stream>>>(Qb, Kb, V4, mb, Opart, Lp);
  attn_merge<<<1024, 256, 0, stream>>>(Opart, Lp, Qb);

  dense_gemm<<<dim3(8, 64), 256, 0, stream>>>(Qb, dwb, db, (float*)d_out);
}

// Round 15
// 230.732 us; speedup vs baseline: 2.2264x; 1.9368x over previous
//
#include <hip/hip_runtime.h>
#include <hip/hip_bf16.h>

#define S_LEN 4096
#define DM    512
#define NH    8
#define DK    64

typedef __attribute__((ext_vector_type(8))) __bf16 bf16x8;
typedef __attribute__((ext_vector_type(4))) float  f32x4;
typedef unsigned short u16;
typedef unsigned int   u32;
typedef unsigned long long u64;

// Q-GEMM epilogue scale: 1/sqrt(64) * log2(e)  (softmax in log2 domain)
#define SQ_SCALE (0.125f * 1.44269504f)
// Fixed softmax shift (log2-domain). Shift-invariant; l-division restores scale.
#define FMAX 12.0f

__device__ __forceinline__ u16 f2bf(float f) {
  union { float f; u32 i; } v; v.f = f;
  u32 r = v.i + 0x7fff + ((v.i >> 16) & 1);   // RNE
  return (u16)(r >> 16);
}
__device__ __forceinline__ float bf2f(u16 u) {
  union { u32 i; float f; } v; v.i = ((u32)u) << 16; return v.f;
}

// ---------------------------------------------------------------------------
// Fused prep: blocks [0,65536) pack mask int32 -> u64 bitmask;
// blocks [65536,68608) convert fp32 -> bf16 (x | wq|wk|wv -> wcat | dw).
__global__ __launch_bounds__(256) void prep(
    const int* __restrict__ mask, u64* __restrict__ mb,
    const float* __restrict__ x, const float* __restrict__ wq,
    const float* __restrict__ wk, const float* __restrict__ wv,
    const float* __restrict__ dw,
    u16* __restrict__ xb, u16* __restrict__ wcat, u16* __restrict__ dwb) {
  int b = blockIdx.x;
  if (b < 65536) {
    int gid = b * 256 + threadIdx.x;
    u64 bb = __ballot(mask[gid] != 0);
    if ((threadIdx.x & 63) == 0) mb[gid >> 6] = bb;
  } else {
    b -= 65536;
    const float* src; u16* dst; size_t off;
    if      (b < 2048) { src = x;  dst = xb;   off = (size_t)b * 1024; }
    else if (b < 2304) { src = wq; dst = wcat; off = (size_t)(b - 2048) * 1024; }
    else if (b < 2560) { src = wk; dst = wcat + 262144; off = (size_t)(b - 2304) * 1024; }
    else if (b < 2816) { src = wv; dst = wcat + 524288; off = (size_t)(b - 2560) * 1024; }
    else               { src = dw; dst = dwb;  off = (size_t)(b - 2816) * 1024; }
    size_t i = off + (size_t)threadIdx.x * 4;
    float4 v = *reinterpret_cast<const float4*>(src + i);
    ushort4 o = make_ushort4(f2bf(v.x), f2bf(v.y), f2bf(v.z), f2bf(v.w));
    *reinterpret_cast<ushort4*>(dst + i) = o;
  }
}

// ---------------------------------------------------------------------------
// Fused QKV projection, 64(m) x 128(n) tiles: C[4096,1536] = x @ Wcat^T + bias.
// grid (12, 64). seg 0=Q (scaled), 1=K, 2=V.
// V output layout V4[(h*64+d)][tile*64 + slot] where for true key kappa =
// m'*8+c (from _split_heads: h=m>>9, d=n&63, key=(m&511)*8+(n>>6)):
// tile = m'>>3, slot = (c&1)*32 + (c>>1)*8 + (m'&7).  This slot order makes
// attn's P C-layout directly usable as the PV A-fragment (see attn_mfma).
__global__ __launch_bounds__(256) void qkv_gemm(
    const u16* __restrict__ A, const u16* __restrict__ Wcat,
    const float* __restrict__ bq, const float* __restrict__ bk,
    const float* __restrict__ bv,
    u16* __restrict__ Qb, u16* __restrict__ Kb, u16* __restrict__ V4) {
  __shared__ u16 As[64 * 72];    // 9.2 KB
  __shared__ u16 Ws[128 * 72];   // 18.4 KB (reused as T in V epilogue)
  const int t = threadIdx.x;
  const int lane = t & 63, wv = t >> 6;
  const int m16 = lane & 15, quad = lane >> 4;
  const int n0g = blockIdx.x * 128, m0 = blockIdx.y * 64;
  const int seg = n0g >> 9;
  const int n0 = n0g & 511;
  const int mq = wv >> 1, nq = wv & 1;   // wave quadrant

  f32x4 acc[2][4];
#pragma unroll
  for (int i = 0; i < 2; i++)
#pragma unroll
    for (int j = 0; j < 4; j++) acc[i][j] = (f32x4)0.f;

  for (int k0 = 0; k0 < DM; k0 += 64) {
    __syncthreads();
#pragma unroll
    for (int c0 = 0; c0 < 2; c0++) {       // A: 64x64 = 512 uint4
      int c = t + c0 * 256;
      int row = c >> 3, col = (c & 7) * 8;
      *reinterpret_cast<uint4*>(&As[row * 72 + col]) =
          *reinterpret_cast<const uint4*>(&A[(size_t)(m0 + row) * DM + k0 + col]);
    }
#pragma unroll
    for (int c0 = 0; c0 < 4; c0++) {       // W: 128x64 = 1024 uint4
      int c = t + c0 * 256;
      int row = c >> 3, col = (c & 7) * 8;
      *reinterpret_cast<uint4*>(&Ws[row * 72 + col]) =
          *reinterpret_cast<const uint4*>(&Wcat[(size_t)(n0g + row) * DM + k0 + col]);
    }
    __syncthreads();
#pragma unroll
    for (int kk = 0; kk < 64; kk += 32) {
      bf16x8 a0 = *reinterpret_cast<const bf16x8*>(&As[(mq * 32 + m16) * 72 + quad * 8 + kk]);
      bf16x8 a1 = *reinterpret_cast<const bf16x8*>(&As[(mq * 32 + 16 + m16) * 72 + quad * 8 + kk]);
#pragma unroll
      for (int ct = 0; ct < 4; ct++) {
        bf16x8 b = *reinterpret_cast<const bf16x8*>(&Ws[(nq * 64 + ct * 16 + m16) * 72 + quad * 8 + kk]);
        acc[0][ct] = __builtin_amdgcn_mfma_f32_16x16x32_bf16(a0, b, acc[0][ct], 0, 0, 0);
        acc[1][ct] = __builtin_amdgcn_mfma_f32_16x16x32_bf16(a1, b, acc[1][ct], 0, 0, 0);
      }
    }
  }

  const float* bias = (seg == 0) ? bq : (seg == 1) ? bk : bv;
  const float scale = (seg == 0) ? SQ_SCALE : 1.f;
  float bn[4];
#pragma unroll
  for (int ct = 0; ct < 4; ct++) bn[ct] = bias[n0 + nq * 64 + ct * 16 + m16];

  if (seg == 2) {
    // transpose through LDS (reuse Ws as T[128 nl][64 ml], stride 72)
    __syncthreads();   // all fragment reads of Ws done
    u16* T = Ws;
#pragma unroll
    for (int rt = 0; rt < 2; rt++)
#pragma unroll
      for (int ct = 0; ct < 4; ct++)
#pragma unroll
        for (int r = 0; r < 4; r++)
          T[(nq * 64 + ct * 16 + m16) * 72 + mq * 32 + rt * 16 + quad * 4 + r] =
              f2bf(acc[rt][ct][r] + bn[ct]);
    __syncthreads();
    const int h    = m0 >> 9;
    const int mp   = m0 & 511;   // multiple of 64
    const int cseg = n0 >> 7;    // 0..3
#pragma unroll
    for (int c0 = 0; c0 < 4; c0++) {       // 1024 uint4 copies
      int c = t + c0 * 256;
      int d  = c >> 4;          // 0..63
      int tl = (c >> 1) & 7;    // 0..7
      int cl = c & 1;           // 0..1
      uint4 v = *reinterpret_cast<const uint4*>(&T[(cl * 64 + d) * 72 + tl * 8]);
      *reinterpret_cast<uint4*>(
          &V4[(size_t)(h * 64 + d) * 4096 + ((mp >> 3) + tl) * 64 + cl * 32 + cseg * 8]) = v;
    }
  } else {
    u16* dst = (seg == 0) ? Qb : Kb;
#pragma unroll
    for (int rt = 0; rt < 2; rt++)
#pragma unroll
      for (int ct = 0; ct < 4; ct++) {
        int n = n0 + nq * 64 + ct * 16 + m16;
#pragma unroll
        for (int r = 0; r < 4; r++) {
          int m = m0 + mq * 32 + rt * 16 + quad * 4 + r;
          dst[(size_t)m * DM + n] = f2bf((acc[rt][ct][r] + bn[ct]) * scale);
        }
      }
  }
}

// ---------------------------------------------------------------------------
// Dense out-proj, 64x64 tiles: C[4096,512](f32) = A @ dw^T + db. grid (8,64).
__global__ __launch_bounds__(256) void dense_gemm(
    const u16* __restrict__ A, const u16* __restrict__ W,
    const float* __restrict__ bias, float* __restrict__ Cout) {
  __shared__ u16 As[64 * 72];
  __shared__ u16 Ws[64 * 72];
  const int t = threadIdx.x;
  const int lane = t & 63, wv = t >> 6;
  const int m16 = lane & 15, quad = lane >> 4;
  const int n0 = blockIdx.x * 64, m0 = blockIdx.y * 64;

  f32x4 acc[4];
#pragma unroll
  for (int j = 0; j < 4; j++) acc[j] = (f32x4)0.f;

  for (int k0 = 0; k0 < DM; k0 += 64) {
    __syncthreads();
#pragma unroll
    for (int c0 = 0; c0 < 2; c0++) {
      int c = t + c0 * 256;
      int row = c >> 3, col = (c & 7) * 8;
      *reinterpret_cast<uint4*>(&As[row * 72 + col]) =
          *reinterpret_cast<const uint4*>(&A[(size_t)(m0 + row) * DM + k0 + col]);
      *reinterpret_cast<uint4*>(&Ws[row * 72 + col]) =
          *reinterpret_cast<const uint4*>(&W[(size_t)(n0 + row) * DM + k0 + col]);
    }
    __syncthreads();
#pragma unroll
    for (int kk = 0; kk < 64; kk += 32) {
      bf16x8 a = *reinterpret_cast<const bf16x8*>(&As[(wv * 16 + m16) * 72 + quad * 8 + kk]);
#pragma unroll
      for (int ct = 0; ct < 4; ct++) {
        bf16x8 b = *reinterpret_cast<const bf16x8*>(&Ws[(ct * 16 + m16) * 72 + quad * 8 + kk]);
        acc[ct] = __builtin_amdgcn_mfma_f32_16x16x32_bf16(a, b, acc[ct], 0, 0, 0);
      }
    }
  }

  float bn[4];
#pragma unroll
  for (int ct = 0; ct < 4; ct++) bn[ct] = bias[n0 + ct * 16 + m16];
#pragma unroll
  for (int ct = 0; ct < 4; ct++) {
    int n = n0 + ct * 16 + m16;
#pragma unroll
    for (int r = 0; r < 4; r++) {
      int m = m0 + wv * 16 + quad * 4 + r;
      Cout[(size_t)m * DM + n] = acc[ct][r] + bn[ct];
    }
  }
}

// ---------------------------------------------------------------------------
// exp2 + mask + pack one q-subtile's scores into the two PV A-fragments.
// Mask bit for C slot (ct,r): true key = 32(ct&1) + 16(r>>1) + 8(r&1)
// + 2*quad + (ct>>1); lo/hi are the lane's mask word pre-shifted by 2*quad.
__device__ __forceinline__ void pack_p(const f32x4* s, u32 lo, u32 hi,
                                       uint4& o0, uint4& o1) {
  u32 pk[8];
#pragma unroll
  for (int ct = 0; ct < 4; ct++) {
    u32 w = (ct & 1) ? hi : lo;
    int b = ct >> 1;
    float p0 = __builtin_amdgcn_exp2f(((w >> b) & 1u)        ? -1e9f : s[ct][0]);
    float p1 = __builtin_amdgcn_exp2f(((w >> (b + 8)) & 1u)  ? -1e9f : s[ct][1]);
    float p2 = __builtin_amdgcn_exp2f(((w >> (b + 16)) & 1u) ? -1e9f : s[ct][2]);
    float p3 = __builtin_amdgcn_exp2f(((w >> (b + 24)) & 1u) ? -1e9f : s[ct][3]);
    pk[2 * ct]     = __builtin_amdgcn_perm(__float_as_uint(p1) + 0x8000u,
                                           __float_as_uint(p0) + 0x8000u, 0x07060302u);
    pk[2 * ct + 1] = __builtin_amdgcn_perm(__float_as_uint(p3) + 0x8000u,
                                           __float_as_uint(p2) + 0x8000u, 0x07060302u);
  }
  o0 = make_uint4(pk[0], pk[1], pk[2], pk[3]);
  o1 = make_uint4(pk[4], pk[5], pk[6], pk[7]);
}

// ---------------------------------------------------------------------------
// Flash attention v3.3: fixed-shift softmax, grid split-K x8, NO P roundtrip.
// Key axis co-permuted in K staging (sigma bit-shuffle) and V4 layout so the
// S^T C-layout registers, exp2'd and bf16-packed, ARE the PV A-fragments.
// Each wave owns 32 q (2 subtiles); block 256 thr = 128 q; grid (32, 8, 8)
// = 2048 blocks = 8 blocks/CU.
// launch_bounds min-waves = 4: the allocator honors the hint by SHRINKING
// VGPRs below the spill-free ~64 (r13: hint 8 -> 32 VGPR, 1.65 GB spill
// traffic; r14: hint 6 -> 40 VGPR, 1.29 GB). Hint 4 gives VGPR=64, zero
// spill (r12-measured); HW co-residency is then set by actual use:
// 64 VGPR -> 8 waves/EU and 8 x 18.4 KB LDS = 147 KB < 160 KB -> the z=8
// grid still co-schedules 8 blocks/CU.
__global__ __launch_bounds__(256, 4) void attn_mfma(
    const u16* __restrict__ Q, const u16* __restrict__ K,
    const u16* __restrict__ V4, const u64* __restrict__ mbits,
    u16* __restrict__ Op, float* __restrict__ Lp) {
  __shared__ u16 Ks[64 * 72];
  __shared__ u16 Vs[64 * 72];

  const int t = threadIdx.x;
  const int lane = t & 63, w4 = t >> 6;
  const int m16 = lane & 15, quad = lane >> 4;
  const int q0 = blockIdx.x * 128;
  const int h = blockIdx.y;
  const int g = blockIdx.z;          // key eighth: 512 keys, 8 tiles
  const size_t hoff = (size_t)h * S_LEN * DK;
  const size_t kbase = hoff + (size_t)g * 512 * DK;

  // Q fragments for the wave's two q-subtiles (pre-scaled in Q-GEMM)
  const u16* qpA = Q + hoff + (size_t)(q0 + w4 * 32 + m16) * DK + quad * 8;
  bf16x8 qloA = *reinterpret_cast<const bf16x8*>(qpA);
  bf16x8 qhiA = *reinterpret_cast<const bf16x8*>(qpA + 32);
  bf16x8 qloB = *reinterpret_cast<const bf16x8*>(qpA + 16 * DK);
  bf16x8 qhiB = *reinterpret_cast<const bf16x8*>(qpA + 16 * DK + 32);

  union { u16 u[8]; bf16x8 v; } onesu;
#pragma unroll
  for (int j = 0; j < 8; j++) onesu.u[j] = 0x3F80;
  const bf16x8 ones = onesu.v;

  f32x4 accA[4], accB[4];
  f32x4 acc_lA = (f32x4)0.f, acc_lB = (f32x4)0.f;
#pragma unroll
  for (int dt = 0; dt < 4; dt++) { accA[dt] = (f32x4)0.f; accB[dt] = (f32x4)0.f; }

  for (int k0 = 0; k0 < 512; k0 += 64) {
    const int kg = g * 512 + k0;
    // stage K rows at sigma(rg) = [k0,k5,k2,k1,k4,k3]; V4 already slot-ordered
#pragma unroll
    for (int c0 = 0; c0 < 2; c0++) {
      int c = t + c0 * 256;
      int rg = c >> 3, cc = c & 7;
      int sr = ((rg & 1) << 5) | (((rg >> 5) & 1) << 4) | (((rg >> 2) & 1) << 3) |
               (((rg >> 1) & 1) << 2) | (((rg >> 4) & 1) << 1) | ((rg >> 3) & 1);
      *reinterpret_cast<uint4*>(&Ks[sr * 72 + cc * 8]) =
          *reinterpret_cast<const uint4*>(&K[kbase + (size_t)(k0 + rg) * DK + cc * 8]);
      *reinterpret_cast<uint4*>(&Vs[rg * 72 + cc * 8]) =
          *reinterpret_cast<const uint4*>(&V4[(size_t)(h * 64 + rg) * 4096 + kg + cc * 8]);
    }
    u64 mqA = mbits[(size_t)(q0 + w4 * 32 + m16) * 64 + (kg >> 6)] >> (2 * quad);
    u64 mqB = mbits[(size_t)(q0 + w4 * 32 + 16 + m16) * 64 + (kg >> 6)] >> (2 * quad);
    __syncthreads();   // tiles ready

    // S^T - FMAX for both q-subtiles; each K fragment feeds 2 MFMAs
    f32x4 sA[4], sB[4];
#pragma unroll
    for (int ct = 0; ct < 4; ct++) { sA[ct] = (f32x4)(-FMAX); sB[ct] = (f32x4)(-FMAX); }
#pragma unroll
    for (int ct = 0; ct < 4; ct++) {
      bf16x8 klo = *reinterpret_cast<const bf16x8*>(&Ks[(ct * 16 + m16) * 72 + quad * 8]);
      bf16x8 khi = *reinterpret_cast<const bf16x8*>(&Ks[(ct * 16 + m16) * 72 + quad * 8 + 32]);
      sA[ct] = __builtin_amdgcn_mfma_f32_16x16x32_bf16(klo, qloA, sA[ct], 0, 0, 0);
      sA[ct] = __builtin_amdgcn_mfma_f32_16x16x32_bf16(khi, qhiA, sA[ct], 0, 0, 0);
      sB[ct] = __builtin_amdgcn_mfma_f32_16x16x32_bf16(klo, qloB, sB[ct], 0, 0, 0);
      sB[ct] = __builtin_amdgcn_mfma_f32_16x16x32_bf16(khi, qhiB, sB[ct], 0, 0, 0);
    }

    // exp2 + pack: registers become the PV A-fragments directly (no LDS)
    union { uint4 i; bf16x8 v; } pA0, pA1, pB0, pB1;
    pack_p(sA, (u32)mqA, (u32)(mqA >> 32), pA0.i, pA1.i);
    pack_p(sB, (u32)mqB, (u32)(mqB >> 32), pB0.i, pB1.i);

    // O += P @ V ; l += P @ 1; each V fragment feeds 2 MFMAs
#pragma unroll
    for (int dt = 0; dt < 4; dt++) {
      bf16x8 vlo = *reinterpret_cast<const bf16x8*>(&Vs[(dt * 16 + m16) * 72 + quad * 8]);
      bf16x8 vhi = *reinterpret_cast<const bf16x8*>(&Vs[(dt * 16 + m16) * 72 + quad * 8 + 32]);
      accA[dt] = __builtin_amdgcn_mfma_f32_16x16x32_bf16(pA0.v, vlo, accA[dt], 0, 0, 0);
      accA[dt] = __builtin_amdgcn_mfma_f32_16x16x32_bf16(pA1.v, vhi, accA[dt], 0, 0, 0);
      accB[dt] = __builtin_amdgcn_mfma_f32_16x16x32_bf16(pB0.v, vlo, accB[dt], 0, 0, 0);
      accB[dt] = __builtin_amdgcn_mfma_f32_16x16x32_bf16(pB1.v, vhi, accB[dt], 0, 0, 0);
    }
    acc_lA = __builtin_amdgcn_mfma_f32_16x16x32_bf16(pA0.v, ones, acc_lA, 0, 0, 0);
    acc_lA = __builtin_amdgcn_mfma_f32_16x16x32_bf16(pA1.v, ones, acc_lA, 0, 0, 0);
    acc_lB = __builtin_amdgcn_mfma_f32_16x16x32_bf16(pB0.v, ones, acc_lB, 0, 0, 0);
    acc_lB = __builtin_amdgcn_mfma_f32_16x16x32_bf16(pB1.v, ones, acc_lB, 0, 0, 0);
    __syncthreads();   // all tile reads done before next staging
  }

  // partial O (unnormalized bf16) + partial l (f32)
  u16* Og = Op + (size_t)g * 2097152;
#pragma unroll
  for (int dt = 0; dt < 4; dt++)
#pragma unroll
    for (int r = 0; r < 4; r++) {
      Og[(size_t)(q0 + w4 * 32 + quad * 4 + r) * DM + h * DK + dt * 16 + m16] =
          f2bf(accA[dt][r]);
      Og[(size_t)(q0 + w4 * 32 + 16 + quad * 4 + r) * DM + h * DK + dt * 16 + m16] =
          f2bf(accB[dt][r]);
    }
  if (m16 == 0) {
#pragma unroll
    for (int r = 0; r < 4; r++) {
      Lp[g * 32768 + h * 4096 + q0 + w4 * 32 + quad * 4 + r] = acc_lA[r];
      Lp[g * 32768 + h * 4096 + q0 + w4 * 32 + 16 + quad * 4 + r] = acc_lB[r];
    }
  }
}

// ---------------------------------------------------------------------------
// Merge the eight key-split partials: Out = sum(O_g) / sum(l_g). bf16 out.
__global__ __launch_bounds__(256) void attn_merge(
    const u16* __restrict__ Op, const float* __restrict__ Lp,
    u16* __restrict__ Out) {
  int i8 = (blockIdx.x * 256 + threadIdx.x) * 8;   // 8 elems/thread, same (q,h)
  int q = i8 >> 9;
  int h = (i8 >> 6) & 7;
  float l = 0.f;
#pragma unroll
  for (int part = 0; part < 8; part++) l += Lp[part * 32768 + h * 4096 + q];
  float rl = 1.f / l;
  float o[8];
#pragma unroll
  for (int j = 0; j < 8; j++) o[j] = 0.f;
#pragma unroll
  for (int part = 0; part < 8; part++) {
    ushort4 v0 = *reinterpret_cast<const ushort4*>(Op + part * 2097152 + i8);
    ushort4 v1 = *reinterpret_cast<const ushort4*>(Op + part * 2097152 + i8 + 4);
    o[0] += bf2f(v0.x); o[1] += bf2f(v0.y); o[2] += bf2f(v0.z); o[3] += bf2f(v0.w);
    o[4] += bf2f(v1.x); o[5] += bf2f(v1.y); o[6] += bf2f(v1.z); o[7] += bf2f(v1.w);
  }
  ushort4 o0 = make_ushort4(f2bf(o[0] * rl), f2bf(o[1] * rl),
                            f2bf(o[2] * rl), f2bf(o[3] * rl));
  ushort4 o1 = make_ushort4(f2bf(o[4] * rl), f2bf(o[5] * rl),
                            f2bf(o[6] * rl), f2bf(o[7] * rl));
  *reinterpret_cast<ushort4*>(Out + i8) = o0;
  *reinterpret_cast<ushort4*>(Out + i8 + 4) = o1;
}

// ---------------------------------------------------------------------------
extern "C" void kernel_launch(void* const* d_in, const int* in_sizes, int n_in,
                              void* d_out, int out_size, void* d_ws, size_t ws_size,
                              hipStream_t stream) {
  const float* x    = (const float*)d_in[0];
  const int*   mask = (const int*)d_in[1];
  const float* wq_w = (const float*)d_in[2];
  const float* wq_b = (const float*)d_in[3];
  const float* wk_w = (const float*)d_in[4];
  const float* wk_b = (const float*)d_in[5];
  const float* wv_w = (const float*)d_in[6];
  const float* wv_b = (const float*)d_in[7];
  const float* dw   = (const float*)d_in[8];
  const float* db   = (const float*)d_in[9];

  // ws (u16 elems): xb 2M | wcat 768K | dwb 256K | Qb/Kb/V4 2M each |
  // Opart 8x2M | mb 256K u64 | Lp 256K f32.  ~53 MB total (ws is ~256 MB).
  u16* xb    = (u16*)d_ws;
  u16* wcat  = xb    + 2097152;
  u16* dwb   = wcat  + 786432;
  u16* Qb    = dwb   + 262144;
  u16* Kb    = Qb    + 2097152;
  u16* V4    = Kb    + 2097152;
  u16* Opart = V4    + 2097152;
  u64* mb    = (u64*)(Opart + 8 * 2097152);
  float* Lp  = (float*)(mb + 262144);

  prep<<<68608, 256, 0, stream>>>(mask, mb, x, wq_w, wk_w, wv_w, dw,
                                  xb, wcat, dwb);

  qkv_gemm<<<dim3(12, 64), 256, 0, stream>>>(xb, wcat, wq_b, wk_b, wv_b,
                                             Qb, Kb, V4);

  attn_mfma<<<dim3(32, NH, 8), 256, 0, stream>>>(Qb, Kb, V4, mb, Opart, Lp);
  attn_merge<<<1024, 256, 0, stream>>>(Opart, Lp, Qb);

  dense_gemm<<<dim3(8, 64), 256, 0, stream>>>(Qb, dwb, db, (float*)d_out);
}